// Round 10
// baseline (53.671 us; speedup 1.0000x reference)
//
#include <hip/hip_runtime.h>

#define BB 8
#define MM 2048
#define HH 1024
#define THRESH 0.99f
#define BMH ((size_t)BB * MM * HH)
#define BM (BB * MM)
#define CHUNK 8
#define NBLK (BM / CHUNK)    // 2048 blocks
#define CPR (MM / CHUNK)     // 256 chunks per batch row

typedef float f32x4 __attribute__((ext_vector_type(4)));

__device__ inline f32x4 ntload4(const float* p) {
    return __builtin_nontemporal_load((const f32x4*)p);
}
__device__ inline void ntstore4(float* p, f32x4 v) {
    __builtin_nontemporal_store(v, (f32x4*)p);
}
__device__ inline f32x4 ld4(const float* p) { return *(const f32x4*)p; }

// ---------------------------------------------------------------------------
// K_dot: read-only gather pass. Per block (8 tokens of one row):
//   scan run-prefix -> rank; dot+sigmoid; scalar outputs; stage
//   upd_ws / rank_ws / per-chunk mc-bitmask for the two heavy kernels.
// ---------------------------------------------------------------------------
__global__ __launch_bounds__(256, 8) void kdot(
    const float* __restrict__ x, const int* __restrict__ run,
    const float* __restrict__ acc_p, const float* __restrict__ remainders,
    const int* __restrict__ exit_, const int* __restrict__ updates,
    const float* __restrict__ p_w, const float* __restrict__ p_b,
    float* __restrict__ out_accp, float* __restrict__ out_rem,
    float* __restrict__ out_run, float* __restrict__ out_exit,
    float* __restrict__ upd_ws, int* __restrict__ rank_ws,
    int* __restrict__ mcmask) {
    __shared__ int wsum[4];
    __shared__ int cflag[CHUNK], crank[CHUNK], cnew[CHUNK];

    const int t0 = blockIdx.x * CHUNK;
    const int b  = t0 >> 11;
    const int m0 = t0 & (MM - 1);
    const int* rrow = run + b * MM;
    const int tid  = threadIdx.x;
    const int wave = tid >> 6;
    const int lane = tid & 63;

    // exclusive prefix count of run[b, 0..m0)
    int s = 0;
    for (int i = tid; i < m0; i += 256) s += (rrow[i] != 0) ? 1 : 0;
#pragma unroll
    for (int off = 32; off > 0; off >>= 1) s += __shfl_xor(s, off, 64);
    if (lane == 0) wsum[wave] = s;
    if (tid < CHUNK) cflag[tid] = (rrow[m0 + tid] != 0) ? 1 : 0;
    __syncthreads();
    const int base0 = wsum[0] + wsum[1] + wsum[2] + wsum[3];
    if (tid < CHUNK) {
        int r = base0;
#pragma unroll
        for (int i = 0; i < CHUNK; ++i) r += (i <= tid) ? cflag[i] : 0;
        crank[tid] = r - 1;
        rank_ws[t0 + tid] = r - 1;
    }
    __syncthreads();

    const float pb = p_b[0];
    const int upd1 = updates[0] + 1;
#pragma unroll
    for (int q = 0; q < 2; ++q) {
        const int ti = wave * 2 + q;
        const int t  = t0 + ti;
        const bool r = (cflag[ti] != 0);
        float dot = 0.f;
        if (r) {
            const float* xrow = x + ((size_t)(b * MM + crank[ti])) * HH;
#pragma unroll
            for (int j = 0; j < 4; ++j) {
                const int idx = j * 256 + lane * 4;
                const f32x4 hv = ld4(xrow + idx);
                const f32x4 wv = ld4(p_w + idx);
                dot += hv.x * wv.x + hv.y * wv.y + hv.z * wv.z + hv.w * wv.w;
            }
        }
#pragma unroll
        for (int off = 32; off > 0; off >>= 1) dot += __shfl_xor(dot, off, 64);

        if (lane == 0) {
            const float p = r ? (1.f / (1.f + expf(-(dot + pb)))) : 0.f;
            const float ap = acc_p[t];
            const bool mc = r && ((ap + p) < THRESH);
            const bool me = r && !mc;
            const float upd = mc ? p : (me ? (1.f - ap) : 0.f);
            const float ap_new = mc ? (ap + p) : ap;
            out_accp[t] = ap_new;
            out_rem[t]  = remainders[t] + (me ? (1.f - ap_new) : 0.f);
            out_run[t]  = mc ? 1.f : 0.f;
            out_exit[t] = (float)(exit_[t] + (me ? upd1 : 0));
            upd_ws[t]   = upd;
            cnew[ti]    = mc ? 1 : 0;
        }
    }
    __syncthreads();
    if (tid == 0) {
        int m16 = 0;
#pragma unroll
        for (int i = 0; i < CHUNK; ++i) m16 |= cnew[i] << i;
        mcmask[blockIdx.x] = m16;
    }
}

// ---------------------------------------------------------------------------
// K_wh: pure stream. out_wh = (run? x_row : 0) * upd + weighted_h.
// No LDS, no barriers, no shuffles; x rows are L3-hot from K_dot.
// ---------------------------------------------------------------------------
__global__ __launch_bounds__(256, 8) void kwh(
    const float* __restrict__ x, const int* __restrict__ run,
    const float* __restrict__ weighted_h, const float* __restrict__ upd_ws,
    const int* __restrict__ rank_ws, float* __restrict__ out_wh) {
    const int t0 = blockIdx.x * CHUNK;
    const int b  = t0 >> 11;
    const int wave = threadIdx.x >> 6;
    const int lane = threadIdx.x & 63;

#pragma unroll
    for (int q = 0; q < 2; ++q) {
        const int ti = wave * 2 + q;
        const int t  = t0 + ti;
        const bool r = (run[t] != 0);
        const float upd = upd_ws[t];
        const float* xrow = x + ((size_t)(b * MM + rank_ws[t])) * HH;
        const float* whrow = weighted_h + (size_t)t * HH;
        float* orow = out_wh + (size_t)t * HH;
#pragma unroll
        for (int j = 0; j < 4; ++j) {
            const int idx = j * 256 + lane * 4;
            const f32x4 w4 = ntload4(whrow + idx);
            f32x4 hv = (f32x4)(0.f);
            if (r) hv = ld4(xrow + idx);
            ntstore4(orow + idx, hv * upd + w4);
        }
    }
}

// ---------------------------------------------------------------------------
// K_pack: rank2/cnt from the 8KB mcmask array (1KB per row, L2-hot popc
// prefix — no row rescan); scatter-copy L3-hot x rows; pad tail.
// ---------------------------------------------------------------------------
__global__ __launch_bounds__(256, 8) void kpack(
    const float* __restrict__ x, const float* __restrict__ pad_h,
    const int* __restrict__ mcmask, const int* __restrict__ rank_ws,
    float* __restrict__ h_packed) {
    __shared__ int wsump[4], wsuma[4];

    const int t0  = blockIdx.x * CHUNK;
    const int b   = t0 >> 11;
    const int m0  = t0 & (MM - 1);
    const int myc = blockIdx.x & (CPR - 1);
    const int tid  = threadIdx.x;
    const int wave = tid >> 6;
    const int lane = tid & 63;

    // popcount prefix over the row's 256 chunk masks (one per thread)
    const int pc = __popc(mcmask[b * CPR + tid] & 0xFF);
    int sp = (tid < myc) ? pc : 0;
    int sa = pc;
#pragma unroll
    for (int off = 32; off > 0; off >>= 1) {
        sp += __shfl_xor(sp, off, 64);
        sa += __shfl_xor(sa, off, 64);
    }
    if (lane == 0) { wsump[wave] = sp; wsuma[wave] = sa; }
    __syncthreads();
    const int baseN = wsump[0] + wsump[1] + wsump[2] + wsump[3];
    const int cnt   = wsuma[0] + wsuma[1] + wsuma[2] + wsuma[3];
    const int mybits = mcmask[blockIdx.x] & 0xFF;

#pragma unroll
    for (int q = 0; q < 2; ++q) {
        const int ti = wave * 2 + q;
        const int t  = t0 + ti;
        const int m  = m0 + ti;
        if ((mybits >> ti) & 1) {
            const int dstrow = baseN + __popc(mybits & ((1 << (ti + 1)) - 1)) - 1;
            const float* src = x + ((size_t)(b * MM + rank_ws[t])) * HH;
            float* dst = h_packed + ((size_t)(b * MM + dstrow)) * HH;
#pragma unroll
            for (int j = 0; j < 4; ++j) {
                const int idx = j * 256 + lane * 4;
                ntstore4(dst + idx, ld4(src + idx));
            }
        }
        if (m >= cnt) {
            float* prow = h_packed + (size_t)t * HH;
#pragma unroll
            for (int j = 0; j < 4; ++j) {
                const int idx = j * 256 + lane * 4;
                ntstore4(prow + idx, ld4(pad_h + idx));   // pad_h is L1-hot
            }
        }
    }
}

extern "C" void kernel_launch(void* const* d_in, const int* in_sizes, int n_in,
                              void* d_out, int out_size, void* d_ws, size_t ws_size,
                              hipStream_t stream) {
    const float* x          = (const float*)d_in[0];
    const int*   run        = (const int*)d_in[1];
    const float* acc_p      = (const float*)d_in[2];
    const float* weighted_h = (const float*)d_in[3];
    const float* remainders = (const float*)d_in[4];
    const int*   exit_      = (const int*)d_in[5];
    const int*   updates    = (const int*)d_in[6];
    const float* pad_h      = (const float*)d_in[7];
    const float* p_w        = (const float*)d_in[8];
    const float* p_b        = (const float*)d_in[9];

    float* out = (float*)d_out;
    float* out_hpacked = out;                    // [B,M,H]
    float* out_wh      = out + BMH;              // [B,M,H]
    float* out_accp    = out + 2 * BMH;          // [B,M,1]
    float* out_rem     = out_accp + BM;          // [B,M,1]
    float* out_run     = out_rem + BM;           // [B,M]
    float* out_exit    = out_run + BM;           // [B,M,1]

    float* upd_ws  = (float*)d_ws;           // [B*M]
    int*   rank_ws = (int*)(upd_ws + BM);    // [B*M]
    int*   mc_ws   = rank_ws + BM;           // [NBLK]

    kdot<<<NBLK, 256, 0, stream>>>(x, run, acc_p, remainders, exit_, updates,
                                   p_w, p_b, out_accp, out_rem, out_run,
                                   out_exit, upd_ws, rank_ws, mc_ws);

    kwh<<<NBLK, 256, 0, stream>>>(x, run, weighted_h, upd_ws, rank_ws, out_wh);

    kpack<<<NBLK, 256, 0, stream>>>(x, pad_h, mc_ws, rank_ws, out_hpacked);
}

// Round 11
// 46.678 us; speedup vs baseline: 1.1498x; 1.1498x over previous
//
#include <hip/hip_runtime.h>

#define BB 8
#define MM 2048
#define HH 1024
#define THRESH 0.99f
#define BMH ((size_t)BB * MM * HH)
#define BM (BB * MM)
#define CHUNK 8
#define NBLK (BM / CHUNK)    // 2048 blocks = 8/CU x 256 CU @ VGPR<=64
#define CPR (MM / CHUNK)     // 256 chunks per batch row

typedef float f32x4 __attribute__((ext_vector_type(4)));

__device__ inline f32x4 ntload4(const float* p) {
    return __builtin_nontemporal_load((const f32x4*)p);
}
__device__ inline void ntstore4(float* p, f32x4 v) {
    __builtin_nontemporal_store(v, (f32x4*)p);
}
__device__ inline f32x4 ld4(const float* p) { return *(const f32x4*)p; }

// ---------------------------------------------------------------------------
// P1: redundant prefix of `run` (int4 reads) -> rank; dot + sigmoid +
//     scalars + weighted_h update (nt streams); publish 8-bit mc mask.
// Each block owns 8 contiguous tokens of one row; 4 waves x 2 tokens.
// ---------------------------------------------------------------------------
__global__ __launch_bounds__(256, 8) void phase1_kernel(
    const float* __restrict__ x, const int* __restrict__ run,
    const float* __restrict__ acc_p, const float* __restrict__ weighted_h,
    const float* __restrict__ remainders, const int* __restrict__ exit_,
    const int* __restrict__ updates, const float* __restrict__ p_w,
    const float* __restrict__ p_b,
    float* __restrict__ out_wh, float* __restrict__ out_accp,
    float* __restrict__ out_rem, float* __restrict__ out_run,
    float* __restrict__ out_exit, int* __restrict__ mcmask,
    int* __restrict__ rank_ws) {
    __shared__ int wsum[4];
    __shared__ int cflag[CHUNK];
    __shared__ int crank[CHUNK];
    __shared__ int cnew[CHUNK];

    const int t0 = blockIdx.x * CHUNK;
    const int b  = t0 >> 11;
    const int m0 = t0 & (MM - 1);
    const int* rrow = run + b * MM;
    const int tid  = threadIdx.x;
    const int wave = tid >> 6;
    const int lane = tid & 63;

    // exclusive prefix count of run[b, 0..m0): int4 strided + shfl reduce
    int s = 0;
    const int n4 = m0 >> 2;   // m0 is a multiple of 8
    const int4* rrow4 = (const int4*)rrow;
    for (int i = tid; i < n4; i += 256) {
        const int4 v = rrow4[i];
        s += (v.x != 0) + (v.y != 0) + (v.z != 0) + (v.w != 0);
    }
#pragma unroll
    for (int off = 32; off > 0; off >>= 1) s += __shfl_xor(s, off, 64);
    if (lane == 0) wsum[wave] = s;
    if (tid < CHUNK) cflag[tid] = (rrow[m0 + tid] != 0) ? 1 : 0;
    __syncthreads();
    const int base0 = wsum[0] + wsum[1] + wsum[2] + wsum[3];
    if (tid < CHUNK) {
        int r = base0;
#pragma unroll
        for (int i = 0; i < CHUNK; ++i) r += (i <= tid) ? cflag[i] : 0;
        crank[tid] = r - 1;
        rank_ws[t0 + tid] = r - 1;
    }
    __syncthreads();

#pragma unroll
    for (int q = 0; q < 2; ++q) {
        const int ti = wave * 2 + q;
        const int t  = t0 + ti;
        const bool r = (cflag[ti] != 0);
        f32x4 hv[4];
        float dot = 0.f;
        if (r) {
            const float* xrow = x + ((size_t)(b * MM + crank[ti])) * HH;
#pragma unroll
            for (int j = 0; j < 4; ++j) {
                const int idx = j * 256 + lane * 4;
                hv[j] = ld4(xrow + idx);
                const f32x4 wv = ld4(p_w + idx);   // L1-hit after first token
                dot += hv[j].x * wv.x + hv[j].y * wv.y +
                       hv[j].z * wv.z + hv[j].w * wv.w;
            }
        } else {
#pragma unroll
            for (int j = 0; j < 4; ++j) hv[j] = (f32x4)(0.f);
        }
#pragma unroll
        for (int off = 32; off > 0; off >>= 1) dot += __shfl_xor(dot, off, 64);

        const float p = r ? (1.f / (1.f + expf(-(dot + p_b[0])))) : 0.f;
        const float ap = acc_p[t];
        const bool mc = r && ((ap + p) < THRESH);
        const bool me = r && !mc;
        const float upd = mc ? p : (me ? (1.f - ap) : 0.f);
        const float ap_new = mc ? (ap + p) : ap;

        const float* whrow = weighted_h + (size_t)t * HH;
        float* orow = out_wh + (size_t)t * HH;
#pragma unroll
        for (int j = 0; j < 4; ++j) {
            const int idx = j * 256 + lane * 4;
            const f32x4 w4 = ntload4(whrow + idx);
            ntstore4(orow + idx, hv[j] * upd + w4);
        }
        if (lane == 0) {
            out_accp[t] = ap_new;
            out_rem[t]  = remainders[t] + (me ? (1.f - ap_new) : 0.f);
            out_run[t]  = mc ? 1.f : 0.f;
            out_exit[t] = (float)(exit_[t] + (me ? (updates[0] + 1) : 0));
            cnew[ti] = mc ? 1 : 0;
        }
    }
    __syncthreads();
    if (tid == 0) {
        int m8 = 0;
#pragma unroll
        for (int i = 0; i < CHUNK; ++i) m8 |= cnew[i] << i;
        mcmask[blockIdx.x] = m8;
    }
}

// ---------------------------------------------------------------------------
// P2: rank2/cnt from the row's 256 chunk masks (1KB, L2-hot popc prefix —
//     no row rescan); scatter-pack x rows (L3-hot); pad tail (nt stores).
// ---------------------------------------------------------------------------
__global__ __launch_bounds__(256, 8) void phase2_kernel(
    const float* __restrict__ x, const float* __restrict__ pad_h,
    const int* __restrict__ mcmask, const int* __restrict__ rank_ws,
    float* __restrict__ h_packed) {
    __shared__ int wsump[4], wsuma[4];

    const int t0  = blockIdx.x * CHUNK;
    const int b   = t0 >> 11;
    const int m0  = t0 & (MM - 1);
    const int myc = blockIdx.x & (CPR - 1);
    const int tid  = threadIdx.x;
    const int wave = tid >> 6;
    const int lane = tid & 63;

    // popcount prefix over this row's 256 chunk masks (one per thread)
    const int mymask = mcmask[b * CPR + tid] & 0xFF;
    const int pc = __popc(mymask);
    int sp = (tid < myc) ? pc : 0;
    int sa = pc;
#pragma unroll
    for (int off = 32; off > 0; off >>= 1) {
        sp += __shfl_xor(sp, off, 64);
        sa += __shfl_xor(sa, off, 64);
    }
    if (lane == 0) { wsump[wave] = sp; wsuma[wave] = sa; }
    __syncthreads();
    const int baseN = wsump[0] + wsump[1] + wsump[2] + wsump[3];
    const int cnt   = wsuma[0] + wsuma[1] + wsuma[2] + wsuma[3];
    const int mybits = mcmask[blockIdx.x] & 0xFF;   // L1-hot re-read

#pragma unroll
    for (int q = 0; q < 2; ++q) {
        const int ti = wave * 2 + q;
        const int t  = t0 + ti;
        const int m  = m0 + ti;
        if ((mybits >> ti) & 1) {
            const int dstrow = baseN + __popc(mybits & ((1 << (ti + 1)) - 1)) - 1;
            const float* src = x + ((size_t)(b * MM + rank_ws[t])) * HH;
            float* dst = h_packed + ((size_t)(b * MM + dstrow)) * HH;
#pragma unroll
            for (int j = 0; j < 4; ++j) {
                const int idx = j * 256 + lane * 4;
                ntstore4(dst + idx, ld4(src + idx));
            }
        }
        if (m >= cnt) {
            float* prow = h_packed + (size_t)t * HH;
#pragma unroll
            for (int j = 0; j < 4; ++j) {
                const int idx = j * 256 + lane * 4;
                ntstore4(prow + idx, ld4(pad_h + idx));   // pad_h is L1-hot
            }
        }
    }
}

extern "C" void kernel_launch(void* const* d_in, const int* in_sizes, int n_in,
                              void* d_out, int out_size, void* d_ws, size_t ws_size,
                              hipStream_t stream) {
    const float* x          = (const float*)d_in[0];
    const int*   run        = (const int*)d_in[1];
    const float* acc_p      = (const float*)d_in[2];
    const float* weighted_h = (const float*)d_in[3];
    const float* remainders = (const float*)d_in[4];
    const int*   exit_      = (const int*)d_in[5];
    const int*   updates    = (const int*)d_in[6];
    const float* pad_h      = (const float*)d_in[7];
    const float* p_w        = (const float*)d_in[8];
    const float* p_b        = (const float*)d_in[9];

    float* out = (float*)d_out;
    float* out_hpacked = out;                    // [B,M,H]
    float* out_wh      = out + BMH;              // [B,M,H]
    float* out_accp    = out + 2 * BMH;          // [B,M,1]
    float* out_rem     = out_accp + BM;          // [B,M,1]
    float* out_run     = out_rem + BM;           // [B,M]
    float* out_exit    = out_run + BM;           // [B,M,1]

    int* mcmask  = (int*)d_ws;          // [NBLK] 8-bit mc masks
    int* rank_ws = mcmask + NBLK;       // [B*M]

    phase1_kernel<<<NBLK, 256, 0, stream>>>(x, run, acc_p, weighted_h, remainders,
                                            exit_, updates, p_w, p_b,
                                            out_wh, out_accp, out_rem, out_run,
                                            out_exit, mcmask, rank_ws);

    phase2_kernel<<<NBLK, 256, 0, stream>>>(x, pad_h, mcmask, rank_ws,
                                            out_hpacked);
}